// Round 4
// baseline (743.344 us; speedup 1.0000x reference)
//
#include <hip/hip_runtime.h>
#include <hip/hip_bf16.h>
#include <math.h>

// RecurrentFFN: B=1024, D=1024, H=4096, C=5120.
// Inputs fp32, outputs fp32 (reference dtypes). Compute: bf16 MFMA.
//   gemm<1>: [x,h]@[W_u|W_r] -> u=sigmoid (fp32, parked in d_out newh region),
//                               rh=sigmoid*h (bf16, ws)
//   gemm<2>: [x,rh]@[W_g|W_up] -> g, up (bf16+bias, ws)
//   ln_h  : t=(2-u)h+u*silu(g)*up, LayerNorm -> new_h fp32 (in-place over u)
//   gemm<3>: new_h@W_d + b_d -> o_pre fp32 (in d_out out region)
//   ln_o  : LayerNorm fp32 in place -> out

typedef unsigned short u16;
typedef unsigned int u32;
typedef __attribute__((ext_vector_type(8))) short short8;
typedef __attribute__((ext_vector_type(4))) float floatx4;

#define B_ROWS 1024
#define H_DIM 4096
#define D_DIM 1024
#define LDA_S 72   // padded As row stride (u16): 64 + 8

__device__ __forceinline__ float bf2f(u16 v) {
  u32 u = ((u32)v) << 16;
  return __builtin_bit_cast(float, u);
}
__device__ __forceinline__ u16 f2bf(float f) {
  u32 u = __builtin_bit_cast(u32, f);
  u32 r = (u + 0x7fffu + ((u >> 16) & 1u)) >> 16;   // round-to-nearest-even
  return (u16)r;
}

// MODE 1: A=[x(f32)|h(f32)], B=[W_u|W_r]; !second -> outF = sigmoid (fp32)
//                                          second  -> outB0 = sigmoid*h (bf16)
// MODE 2: A=[x(f32)|rh(bf16)], B=[W_g|W_up]; !second -> outB0=g, second -> outB1=up (bf16)
// MODE 3: A=new_h(f32), B=W_d; outF = preact+bias (fp32)
template <int MODE>
__launch_bounds__(256)
__global__ void gemm_k(const float* __restrict__ Af0, const float* __restrict__ Af1,
                       const u16* __restrict__ Ab,
                       const float* __restrict__ Bg0, const float* __restrict__ Bg1,
                       const float* __restrict__ bias0, const float* __restrict__ bias1,
                       const float* __restrict__ hglob,
                       float* __restrict__ outF, u16* __restrict__ outB0,
                       u16* __restrict__ outB1) {
  constexpr int K_TOT = (MODE == 3) ? 4096 : 5120;
  constexpr int KT = K_TOT / 64;
  constexpr int LDB = (MODE == 3) ? 1024 : 4096;

  const int n0 = blockIdx.x * 128;
  const int m0 = blockIdx.y * 128;
  const bool second = (MODE != 3) && (n0 >= 4096);
  const float* __restrict__ Bg = second ? Bg1 : Bg0;
  const int ncol0 = second ? (n0 - 4096) : n0;

  __shared__ __align__(16) u16 As[128 * LDA_S];   // [row][k] bf16, +8 pad
  __shared__ __align__(16) u16 Bs[64 * 128];      // [k/8][n][8] bf16, k-contiguous

  const int t = threadIdx.x;
  const int w = t >> 6;
  const int lane = t & 63;
  const int q = lane >> 4;
  const int i16 = lane & 15;
  const int wm = (w >> 1) * 64;
  const int wn = (w & 1) * 64;

  floatx4 acc[4][4] = {};

  for (int kt = 0; kt < KT; ++kt) {
    const int k0 = kt * 64;
    // ---- stage A -> As (bf16), 128 rows x 64 k ----
    const bool a_is_bf16 = (MODE == 2) && (k0 >= 1024);
    if (a_is_bf16) {
      const u16* Ag = Ab;
      const int lda = 4096;
      const int krel = k0 - 1024;
#pragma unroll
      for (int c = 0; c < 4; ++c) {
        const int p = c * 256 + t;           // 16B-chunk (8 u16) index 0..1023
        const int row = p >> 3;
        const int cp = p & 7;
        const uint4 v = *(const uint4*)(Ag + (size_t)(m0 + row) * lda + krel + cp * 8);
        *(uint4*)(&As[row * LDA_S + cp * 8]) = v;
      }
    } else {
      const float* Ag;
      int lda, krel;
      if (MODE == 3)      { Ag = Af0; lda = 4096; krel = k0; }
      else if (k0 < 1024) { Ag = Af0; lda = 1024; krel = k0; }
      else                { Ag = Af1; lda = 4096; krel = k0 - 1024; }
#pragma unroll
      for (int c = 0; c < 8; ++c) {
        const int p = c * 256 + t;           // float4 chunk index 0..2047
        const int row = p >> 4;
        const int cp = p & 15;
        const float4 v = *(const float4*)(Ag + (size_t)(m0 + row) * lda + krel + cp * 4);
        ushort4 o;
        o.x = f2bf(v.x); o.y = f2bf(v.y); o.z = f2bf(v.z); o.w = f2bf(v.w);
        *(ushort4*)(&As[row * LDA_S + cp * 4]) = o;
      }
    }
    // ---- stage B (fp32 -> bf16) with in-register transpose: [K,N] -> [k/8][n][8] ----
#pragma unroll
    for (int cc = 0; cc < 2; ++cc) {
      const int c = 2 * w + cc;              // k-chunk 0..7
      const float* bp = Bg + (size_t)(k0 + c * 8) * LDB + ncol0;
#pragma unroll
      for (int hn = 0; hn < 2; ++hn) {
        const int n = lane + hn * 64;
        const float* src = bp + n;
        u32 p0 = (u32)f2bf(src[0 * LDB]) | ((u32)f2bf(src[1 * LDB]) << 16);
        u32 p1 = (u32)f2bf(src[2 * LDB]) | ((u32)f2bf(src[3 * LDB]) << 16);
        u32 p2 = (u32)f2bf(src[4 * LDB]) | ((u32)f2bf(src[5 * LDB]) << 16);
        u32 p3 = (u32)f2bf(src[6 * LDB]) | ((u32)f2bf(src[7 * LDB]) << 16);
        *(uint4*)(&Bs[(size_t)(c * 128 + n) * 8]) = make_uint4(p0, p1, p2, p3);
      }
    }
    __syncthreads();
    // ---- MFMA: 2 k-steps of 32, 4x4 tiles of 16x16 per wave ----
#pragma unroll
    for (int s = 0; s < 2; ++s) {
      short8 av[4], bv[4];
#pragma unroll
      for (int tm = 0; tm < 4; ++tm) {
        const int r = wm + tm * 16 + i16;
        av[tm] = *(const short8*)(&As[r * LDA_S + (s * 4 + q) * 8]);
      }
#pragma unroll
      for (int tn = 0; tn < 4; ++tn) {
        const int n = wn + tn * 16 + i16;
        const int c = s * 4 + q;
        bv[tn] = *(const short8*)(&Bs[(size_t)(c * 128 + n) * 8]);
      }
#pragma unroll
      for (int tm = 0; tm < 4; ++tm)
#pragma unroll
        for (int tn = 0; tn < 4; ++tn)
          acc[tm][tn] = __builtin_amdgcn_mfma_f32_16x16x32_bf16(av[tm], bv[tn], acc[tm][tn], 0, 0, 0);
    }
    __syncthreads();
  }

  // ---- epilogue ----
  const float* __restrict__ biasP = second ? bias1 : bias0;
  constexpr int LDO = (MODE == 3) ? 1024 : 4096;
#pragma unroll
  for (int tm = 0; tm < 4; ++tm) {
#pragma unroll
    for (int tn = 0; tn < 4; ++tn) {
      const int nloc = ncol0 + wn + tn * 16 + i16;
      const float b = biasP[nloc];
      const int mbase = m0 + wm + tm * 16 + q * 4;
#pragma unroll
      for (int r = 0; r < 4; ++r) {
        const int m = mbase + r;
        const float v = acc[tm][tn][r] + b;
        const size_t oidx = (size_t)m * LDO + nloc;
        if (MODE == 1) {
          const float sg = 1.f / (1.f + __expf(-v));
          if (!second) outF[oidx] = sg;                       // u gate, fp32
          else         outB0[oidx] = f2bf(sg * hglob[oidx]);  // r*h, bf16
        } else if (MODE == 2) {
          if (!second) outB0[oidx] = f2bf(v);                 // gate pre-act
          else         outB1[oidx] = f2bf(v);                 // up pre-act
        } else {
          outF[oidx] = v;                                     // down-proj pre-act
        }
      }
    }
  }
}

// u_f (fp32) ALIASES out (in-place, same offsets): reads precede barrier,
// writes after; one block owns one row. No __restrict__ on those two.
__launch_bounds__(256)
__global__ void ln_h_k(const float* u_f, const u16* __restrict__ wsg,
                       const u16* __restrict__ wsup, const float* __restrict__ h,
                       const float* __restrict__ gamma, const float* __restrict__ beta,
                       float* out) {
  const int row = blockIdx.x, t = threadIdx.x;
  const size_t base = (size_t)row * H_DIM;
  const int i0 = t * 16;
  float tv[16];
  float s = 0.f, s2 = 0.f;
#pragma unroll
  for (int j = 0; j < 16; ++j) {
    const int idx = i0 + j;
    const float u = u_f[base + idx];
    const float g = bf2f(wsg[base + idx]);
    const float up = bf2f(wsup[base + idx]);
    const float hh = h[base + idx];
    const float sw = (g / (1.f + __expf(-g))) * up;   // silu(g)*up
    const float x = (2.f - u) * hh + u * sw;
    tv[j] = x; s += x; s2 += x * x;
  }
#pragma unroll
  for (int off = 32; off; off >>= 1) {
    s += __shfl_down(s, off);
    s2 += __shfl_down(s2, off);
  }
  __shared__ float red[8];
  const int w = t >> 6, lane = t & 63;
  if (lane == 0) { red[w] = s; red[4 + w] = s2; }
  __syncthreads();
  const float S = red[0] + red[1] + red[2] + red[3];
  const float S2 = red[4] + red[5] + red[6] + red[7];
  const float mean = S * (1.f / (float)H_DIM);
  const float var = fmaxf(S2 * (1.f / (float)H_DIM) - mean * mean, 0.f);
  const float rstd = rsqrtf(var + 1e-3f);
#pragma unroll
  for (int j = 0; j < 16; ++j) {
    const int idx = i0 + j;
    out[base + idx] = (tv[j] - mean) * rstd * gamma[idx] + beta[idx];
  }
}

// In-place LN over fp32 region (same offsets) — alias-safe as above.
__launch_bounds__(256)
__global__ void ln_o_k(float* io, const float* __restrict__ gamma,
                       const float* __restrict__ beta) {
  const int row = blockIdx.x, t = threadIdx.x;
  const size_t base = (size_t)row * D_DIM;
  const int i0 = t * 4;
  float tv[4];
  float s = 0.f, s2 = 0.f;
#pragma unroll
  for (int j = 0; j < 4; ++j) {
    const float x = io[base + i0 + j];
    tv[j] = x; s += x; s2 += x * x;
  }
#pragma unroll
  for (int off = 32; off; off >>= 1) {
    s += __shfl_down(s, off);
    s2 += __shfl_down(s2, off);
  }
  __shared__ float red[8];
  const int w = t >> 6, lane = t & 63;
  if (lane == 0) { red[w] = s; red[4 + w] = s2; }
  __syncthreads();
  const float S = red[0] + red[1] + red[2] + red[3];
  const float S2 = red[4] + red[5] + red[6] + red[7];
  const float mean = S * (1.f / (float)D_DIM);
  const float var = fmaxf(S2 * (1.f / (float)D_DIM) - mean * mean, 0.f);
  const float rstd = rsqrtf(var + 1e-3f);
#pragma unroll
  for (int j = 0; j < 4; ++j) {
    const int idx = i0 + j;
    io[base + idx] = (tv[j] - mean) * rstd * gamma[idx] + beta[idx];
  }
}

extern "C" void kernel_launch(void* const* d_in, const int* in_sizes, int n_in,
                              void* d_out, int out_size, void* d_ws, size_t ws_size,
                              hipStream_t stream) {
  (void)in_sizes; (void)n_in; (void)out_size; (void)ws_size;
  const float* x       = (const float*)d_in[0];
  const float* h       = (const float*)d_in[1];
  const float* W_u     = (const float*)d_in[2];
  const float* b_u     = (const float*)d_in[3];
  const float* W_r     = (const float*)d_in[4];
  const float* b_r     = (const float*)d_in[5];
  const float* W_g     = (const float*)d_in[6];
  const float* b_g     = (const float*)d_in[7];
  const float* W_up    = (const float*)d_in[8];
  const float* b_up    = (const float*)d_in[9];
  const float* W_d     = (const float*)d_in[10];
  const float* b_d     = (const float*)d_in[11];
  const float* gamma_h = (const float*)d_in[12];
  const float* beta_h  = (const float*)d_in[13];
  const float* gamma_o = (const float*)d_in[14];
  const float* beta_o  = (const float*)d_in[15];

  float* out_final = (float*)d_out;                              // [B,D] fp32
  float* out_newh  = (float*)d_out + (size_t)B_ROWS * D_DIM;     // [B,H] fp32

  // Workspace: 24 MB bf16 intermediates.
  char* ws = (char*)d_ws;
  u16* ws_rh = (u16*)(ws);                              // B*H bf16 = 8 MB
  u16* ws_g  = (u16*)(ws + (size_t)8 * 1024 * 1024);    // 8 MB
  u16* ws_up = (u16*)(ws + (size_t)16 * 1024 * 1024);   // 8 MB
  float* u_buf = out_newh;   // u gate fp32 parked in d_out newh region (in-place LN later)
  float* o_pre = out_final;  // GEMM3 pre-act fp32 in d_out out region (in-place LN later)

  dim3 blk(256);
  gemm_k<1><<<dim3(64, 8), blk, 0, stream>>>(x, h, nullptr, W_u, W_r, b_u, b_r, h,
                                             u_buf, ws_rh, nullptr);
  gemm_k<2><<<dim3(64, 8), blk, 0, stream>>>(x, nullptr, ws_rh, W_g, W_up, b_g, b_up,
                                             nullptr, nullptr, ws_g, ws_up);
  ln_h_k<<<dim3(B_ROWS), blk, 0, stream>>>(u_buf, ws_g, ws_up, h, gamma_h, beta_h, out_newh);
  gemm_k<3><<<dim3(8, 8), blk, 0, stream>>>(out_newh, nullptr, nullptr, W_d, nullptr,
                                            b_d, nullptr, nullptr, o_pre, nullptr, nullptr);
  ln_o_k<<<dim3(B_ROWS), blk, 0, stream>>>(o_pre, gamma_o, beta_o);
}